// Round 17
// baseline (490.066 us; speedup 1.0000x reference)
//
#include <hip/hip_runtime.h>
#include <hip/hip_fp16.h>
#include <math.h>

#define NN 50000
#define NE 500000
#define EG_BLOCKS ((NE + 255) / 256)

typedef __attribute__((ext_vector_type(8))) short bf16x8;
typedef __attribute__((ext_vector_type(4))) float f32x4;

__device__ __forceinline__ float silu_f(float x) {
  return x / (1.0f + __expf(-x));
}
// fp32 -> bf16 (RNE)
__device__ __forceinline__ unsigned short f2bf(float x) {
  union { float f; unsigned u; } v;
  v.f = x;
  unsigned r = v.u + 0x7fffu + ((v.u >> 16) & 1u);
  return (unsigned short)(r >> 16);
}
// fp32 <-> fp16
__device__ __forceinline__ unsigned short f2h(float x) {
  __half h = __float2half(x);
  return *reinterpret_cast<unsigned short*>(&h);
}
__device__ __forceinline__ float h2f(unsigned short u) {
  __half h = *reinterpret_cast<__half*>(&u);
  return __half2float(h);
}
// split fp32 into bf16 hi + bf16 lo (x ~= hi + lo, ~2^-16 rel err)
__device__ __forceinline__ void splitbf(float x, unsigned short& hi_,
                                        unsigned short& lo_) {
  unsigned short h = f2bf(x);
  union { unsigned u; float f; } v;
  v.u = (unsigned)h << 16;
  hi_ = h;
  lo_ = f2bf(x - v.f);
}
// swizzled index into a [rows][64] bf16 tile: XOR 16B-unit with row&7
__device__ __forceinline__ int swz64(int row, int col) {
  return row * 64 + ((((col >> 3) ^ (row & 7)) << 3) | (col & 7));
}
// swizzled index into a [rows][32] bf16 tile: XOR 16B-unit with row&3
__device__ __forceinline__ int swz32(int row, int col) {
  return row * 32 + ((((col >> 3) ^ (row & 3)) << 3) | (col & 7));
}
// weight B-frag read from swizzled [64 out][64 in] bf16 tile (LDS or global)
__device__ __forceinline__ bf16x8 wfrag(const unsigned short* Wt, int n,
                                        int kc, int q) {
  return *reinterpret_cast<const bf16x8*>(
      &Wt[n * 64 + (((kc * 4 + q) ^ (n & 7)) << 3)]);
}
// A-frag from 8 consecutive fp32 (single bf16)
__device__ __forceinline__ bf16x8 ldfrag(const float* p) {
  float4 f0 = *reinterpret_cast<const float4*>(p);
  float4 f1 = *reinterpret_cast<const float4*>(p + 4);
  bf16x8 a;
  a[0] = (short)f2bf(f0.x); a[1] = (short)f2bf(f0.y);
  a[2] = (short)f2bf(f0.z); a[3] = (short)f2bf(f0.w);
  a[4] = (short)f2bf(f1.x); a[5] = (short)f2bf(f1.y);
  a[6] = (short)f2bf(f1.z); a[7] = (short)f2bf(f1.w);
  return a;
}
// A-frag from 8 consecutive fp32, split hi/lo
__device__ __forceinline__ void ldfrag2(const float* p, bf16x8& hi,
                                        bf16x8& lo) {
  float4 f0 = *reinterpret_cast<const float4*>(p);
  float4 f1 = *reinterpret_cast<const float4*>(p + 4);
  float a[8] = {f0.x, f0.y, f0.z, f0.w, f1.x, f1.y, f1.z, f1.w};
#pragma unroll
  for (int i = 0; i < 8; ++i) {
    unsigned short h, l2;
    splitbf(a[i], h, l2);
    hi[i] = (short)h;
    lo[i] = (short)l2;
  }
}
__device__ __forceinline__ f32x4 mfma_(bf16x8 a, bf16x8 b, f32x4 cacc) {
  return __builtin_amdgcn_mfma_f32_16x16x32_bf16(a, b, cacc, 0, 0, 0);
}

// ---------- Fused: ksort1 (hist) + kprep (swizzle 6 knode tiles) ----------
// Blocks [0,EG): histogram. Blocks [EG,EG+96): write the 6 pre-swizzled
// global weight tiles knode reads directly (4 lo tiles + Wsc0/Wsc1).
__global__ __launch_bounds__(256) void ksort1_prep(
    const int* __restrict__ eidx, int* __restrict__ hist,
    const float* __restrict__ Wl0, const float* __restrict__ Wl1,
    const float* __restrict__ WB0, const float* __restrict__ WB1,
    const float* __restrict__ Wsc0, const float* __restrict__ Wsc1,
    unsigned short* __restrict__ wswz) {
  if (blockIdx.x < EG_BLOCKS) {
    int e = blockIdx.x * 256 + threadIdx.x;
    if (e < NE) atomicAdd(&hist[eidx[NE + e]], 1);
    return;
  }
  const int idx = (blockIdx.x - EG_BLOCKS) * 256 + threadIdx.x;  // 0..24575
  const int tile = idx >> 12, i = idx & 4095;
  const int k = i >> 6, o = i & 63;
  const int s = swz64(o, k);
  unsigned short hi, lo, v;
  switch (tile) {
    case 0: splitbf(Wl0[i], hi, lo); v = lo; break;
    case 1: splitbf(Wl1[i], hi, lo); v = lo; break;
    case 2: splitbf(WB0[i], hi, lo); v = lo; break;
    case 3: splitbf(WB1[i], hi, lo); v = lo; break;
    case 4: v = f2bf(Wsc0[i]); break;
    default: v = f2bf(Wsc1[i]); break;
  }
  wswz[tile * 4096 + s] = v;
}

__global__ __launch_bounds__(1024) void ksort2(const int* __restrict__ hist,
                                               int* __restrict__ cursor) {
  __shared__ int bs[1024];
  const int t = threadIdx.x;
  const int CH = (NN + 1023) / 1024;  // 49
  const int lo = t * CH, hi = (lo + CH < NN) ? lo + CH : NN;
  int s = 0;
  for (int i = lo; i < hi; ++i) s += hist[i];
  bs[t] = s;
  __syncthreads();
  for (int off = 1; off < 1024; off <<= 1) {
    int v = (t >= off) ? bs[t - off] : 0;
    __syncthreads();
    bs[t] += v;
    __syncthreads();
  }
  int run = bs[t] - s;  // exclusive prefix
  for (int i = lo; i < hi; ++i) {
    cursor[i] = run;
    run += hist[i];
  }
}

// ---------- Fused: ksort3 (scatter-permute) + kup (up-projections) ----------
__global__ __launch_bounds__(256) void ksort3_kup(
    const int* __restrict__ eidx, int* __restrict__ cursor,
    int* __restrict__ perm, const float* __restrict__ h,
    const float* __restrict__ Wup0, const float* __restrict__ Wup1,
    unsigned short* __restrict__ upb) {
  __shared__ float shd[4][256];
  if (blockIdx.x < EG_BLOCKS) {
    int e = blockIdx.x * 256 + threadIdx.x;
    if (e < NE) {
      int p = atomicAdd(&cursor[eidx[NE + e]], 1);
      perm[p] = e;
    }
    return;
  }
  const int w = threadIdx.x >> 6, j = threadIdx.x & 63;
  const int n = (blockIdx.x - EG_BLOCKS) * 4 + w;
  const float* hr = h + (size_t)n * 256;
#pragma unroll
  for (int t = 0; t < 4; ++t) shd[w][t * 64 + j] = hr[t * 64 + j];
  __syncthreads();  // cross-lane LDS handoff: always fence
  float a0 = 0.f, ax = 0.f, ay = 0.f, az = 0.f;
#pragma unroll 8
  for (int c = 0; c < 64; ++c) {
    float h0 = shd[w][c];
    float hx = shd[w][64 + 3 * c + 0];
    float hy = shd[w][64 + 3 * c + 1];
    float hz = shd[w][64 + 3 * c + 2];
    float w0 = Wup0[c * 64 + j];
    float w1 = Wup1[c * 64 + j];
    a0 = fmaf(h0, w0, a0);
    ax = fmaf(hx, w1, ax);
    ay = fmaf(hy, w1, ay);
    az = fmaf(hz, w1, az);
  }
  ushort4 pk;
  pk.x = f2h(a0);
  pk.y = f2h(ax);
  pk.z = f2h(ay);
  pk.w = f2h(az);
  *reinterpret_cast<ushort4*>(upb + ((size_t)n * 64 + j) * 4) = pk;
}

// ------------- Kernel B: MFMA edge MLP + messages + merged atomic scatter ----
// R13-exact (validated best: 220 us, absmax 0.75).
__global__ __launch_bounds__(512) void kedge(
    const float* __restrict__ rbf, const int* __restrict__ eidx,
    const float* __restrict__ esh, const float* __restrict__ M1,
    const float* __restrict__ M2, const float* __restrict__ M3,
    const float* __restrict__ M4, const unsigned short* __restrict__ upb,
    const int* __restrict__ perm, float* __restrict__ msg0,
    float* __restrict__ msg1) {
  __shared__ unsigned short M1t[64 * 32];      // [out 64][in 32 (16 zero-pad)]
  __shared__ unsigned short M2t[64 * 64];      // [out][in]
  __shared__ unsigned short M3t[64 * 64];
  __shared__ unsigned short M4t[256 * 64];     // [out 256][in 64]
  __shared__ unsigned short actS[8][32 * 64];  // per-wave [slot 32][ch 64]
  const int tid = threadIdx.x;
  const int w = tid >> 6, l = tid & 63;
  const int c = l & 15, q = l >> 4;

  for (int i = tid; i < 2048; i += 512) {
    int o = i >> 5, k = i & 31;
    M1t[swz32(o, k)] = (k < 16) ? f2bf(M1[k * 64 + o]) : (unsigned short)0;
  }
  for (int i = tid; i < 4096; i += 512) {
    int k = i >> 6, o = i & 63;
    M2t[swz64(o, k)] = f2bf(M2[i]);
    M3t[swz64(o, k)] = f2bf(M3[i]);
  }
  for (int i = tid; i < 16384; i += 512) {
    int k = i >> 8, o = i & 255;
    M4t[swz64(o, k)] = f2bf(M4[i]);
  }
  __syncthreads();

  unsigned short* act = actS[w];
  const float inv3 = 0.57735026918962576f;
  const int NW = NE / 32;  // 15625 wave-groups of 32 sorted edges
  const int scq = (c >> 2) * 8 + (c & 3);  // slot of A-row c, tile 0

  for (int grp = blockIdx.x; grp < (NW + 7) / 8; grp += gridDim.x) {
    const int gw = grp * 8 + w;
    if (gw >= NW) continue;
    const int eb = gw * 32;

    // ---- MLP L1-L3 for both tiles; act rows = sorted slots ----
#pragma unroll
    for (int t = 0; t < 2; ++t) {
      const int sc = scq + t * 4;  // slot of A-row c in tile t
      bf16x8 a1 = {};
      if (q < 2) {
        const int pec = perm[eb + sc];
        const float* p = rbf + (size_t)pec * 16 + q * 8;
        float4 f0 = *reinterpret_cast<const float4*>(p);
        float4 f1 = *reinterpret_cast<const float4*>(p + 4);
        a1[0] = (short)f2bf(f0.x); a1[1] = (short)f2bf(f0.y);
        a1[2] = (short)f2bf(f0.z); a1[3] = (short)f2bf(f0.w);
        a1[4] = (short)f2bf(f1.x); a1[5] = (short)f2bf(f1.y);
        a1[6] = (short)f2bf(f1.z); a1[7] = (short)f2bf(f1.w);
      }
      f32x4 acc[4];
#pragma unroll
      for (int nt = 0; nt < 4; ++nt) {
        int n = nt * 16 + c;
        bf16x8 b = *reinterpret_cast<const bf16x8*>(&M1t[n * 32 + ((q ^ (n & 3)) << 3)]);
        f32x4 z = {0.f, 0.f, 0.f, 0.f};
        acc[nt] = __builtin_amdgcn_mfma_f32_16x16x32_bf16(a1, b, z, 0, 0, 0);
      }
#pragma unroll
      for (int nt = 0; nt < 4; ++nt)
#pragma unroll
        for (int r = 0; r < 4; ++r)
          act[swz64(q * 8 + t * 4 + r, nt * 16 + c)] = f2bf(silu_f(acc[nt][r]));

      // L2
      {
        bf16x8 a0 = *reinterpret_cast<const bf16x8*>(&act[sc * 64 + (((0 + q) ^ (sc & 7)) << 3)]);
        bf16x8 a1b = *reinterpret_cast<const bf16x8*>(&act[sc * 64 + (((4 + q) ^ (sc & 7)) << 3)]);
#pragma unroll
        for (int nt = 0; nt < 4; ++nt) {
          int n = nt * 16 + c;
          f32x4 z = {0.f, 0.f, 0.f, 0.f};
          acc[nt] = __builtin_amdgcn_mfma_f32_16x16x32_bf16(a0, wfrag(M2t, n, 0, q), z, 0, 0, 0);
          acc[nt] = __builtin_amdgcn_mfma_f32_16x16x32_bf16(a1b, wfrag(M2t, n, 1, q), acc[nt], 0, 0, 0);
        }
#pragma unroll
        for (int nt = 0; nt < 4; ++nt)
#pragma unroll
          for (int r = 0; r < 4; ++r)
            act[swz64(q * 8 + t * 4 + r, nt * 16 + c)] = f2bf(silu_f(acc[nt][r]));
      }
      // L3
      {
        bf16x8 a0 = *reinterpret_cast<const bf16x8*>(&act[sc * 64 + (((0 + q) ^ (sc & 7)) << 3)]);
        bf16x8 a1b = *reinterpret_cast<const bf16x8*>(&act[sc * 64 + (((4 + q) ^ (sc & 7)) << 3)]);
#pragma unroll
        for (int nt = 0; nt < 4; ++nt) {
          int n = nt * 16 + c;
          f32x4 z = {0.f, 0.f, 0.f, 0.f};
          acc[nt] = __builtin_amdgcn_mfma_f32_16x16x32_bf16(a0, wfrag(M3t, n, 0, q), z, 0, 0, 0);
          acc[nt] = __builtin_amdgcn_mfma_f32_16x16x32_bf16(a1b, wfrag(M3t, n, 1, q), acc[nt], 0, 0, 0);
        }
#pragma unroll
        for (int nt = 0; nt < 4; ++nt)
#pragma unroll
          for (int r = 0; r < 4; ++r)
            act[swz64(q * 8 + t * 4 + r, nt * 16 + c)] = f2bf(silu_f(acc[nt][r]));
      }
    }

    // ---- metadata for this lane's 8 consecutive sorted slots ----
    int sn[8], rvv[8];
    float4 shv[8];
#pragma unroll
    for (int r8 = 0; r8 < 8; ++r8) {
      const int e2 = perm[eb + 8 * q + r8];
      sn[r8] = eidx[e2];
      rvv[r8] = eidx[NE + e2];
      shv[r8] = *reinterpret_cast<const float4*>(esh + (size_t)e2 * 4);
    }
    // ---- hoist final-act A-frags per tile ----
    bf16x8 a0t[2], a1t[2];
#pragma unroll
    for (int t = 0; t < 2; ++t) {
      const int sc = scq + t * 4;
      a0t[t] = *reinterpret_cast<const bf16x8*>(&act[sc * 64 + (((0 + q) ^ (sc & 7)) << 3)]);
      a1t[t] = *reinterpret_cast<const bf16x8*>(&act[sc * 64 + (((4 + q) ^ (sc & 7)) << 3)]);
    }
    // ---- L4 fused with scatter; chain spans 8 consecutive sorted edges ----
#pragma unroll
    for (int j2 = 0; j2 < 4; ++j2) {
      const int ch = j2 * 16 + c;
      float acc0 = 0.f, accx = 0.f, accy = 0.f, accz = 0.f;
      int cur = rvv[0];
#pragma unroll
      for (int t = 0; t < 2; ++t) {
        ushort4 xv[4];
#pragma unroll
        for (int r = 0; r < 4; ++r)
          xv[r] = *reinterpret_cast<const ushort4*>(
              upb + ((size_t)sn[4 * t + r] * 64 + ch) * 4);
        f32x4 t4[4];
#pragma unroll
        for (int m = 0; m < 4; ++m) {
          int n = (m * 4 + j2) * 16 + c;
          f32x4 z = {0.f, 0.f, 0.f, 0.f};
          t4[m] = __builtin_amdgcn_mfma_f32_16x16x32_bf16(a0t[t], wfrag(M4t, n, 0, q), z, 0, 0, 0);
          t4[m] = __builtin_amdgcn_mfma_f32_16x16x32_bf16(a1t[t], wfrag(M4t, n, 1, q), t4[m], 0, 0, 0);
        }
#pragma unroll
        for (int r = 0; r < 4; ++r) {
          const int idx = 4 * t + r;
          float x0 = h2f(xv[r].x);
          float xx = h2f(xv[r].y);
          float xy = h2f(xv[r].z);
          float xz = h2f(xv[r].w);
          float t0v = t4[0][r], t1v = t4[1][r];
          float t2v = t4[2][r], t3v = t4[3][r];
          float4 sh4 = shv[idx];
          float dot = xx * sh4.y + xy * sh4.z + xz * sh4.w;
          float m0 = t0v * x0 * sh4.x + t3v * dot * inv3;
          float a1v = t1v * x0, b1v = t2v * sh4.x;
          float m1x = fmaf(a1v, sh4.y, b1v * xx);
          float m1y = fmaf(a1v, sh4.z, b1v * xy);
          float m1z = fmaf(a1v, sh4.w, b1v * xz);
          if (rvv[idx] != cur) {
            atomicAdd(msg0 + (size_t)cur * 64 + ch, acc0);
            atomicAdd(msg1 + (size_t)cur * 192 + ch, accx);
            atomicAdd(msg1 + (size_t)cur * 192 + 64 + ch, accy);
            atomicAdd(msg1 + (size_t)cur * 192 + 128 + ch, accz);
            cur = rvv[idx];
            acc0 = accx = accy = accz = 0.f;
          }
          acc0 += m0;
          accx += m1x;
          accy += m1y;
          accz += m1z;
        }
      }
      atomicAdd(msg0 + (size_t)cur * 64 + ch, acc0);
      atomicAdd(msg1 + (size_t)cur * 192 + ch, accx);
      atomicAdd(msg1 + (size_t)cur * 192 + 64 + ch, accy);
      atomicAdd(msg1 + (size_t)cur * 192 + 128 + ch, accz);
    }
  }
}

// ------------- Kernel C: MFMA node path, split-bf16, FULLY FENCED ----------
// Numerics identical to R10 (hi = f2bf; lo tiles + Wsc read from the
// pre-swizzled global copy). LDS 64KB -> 2 blocks/CU.
__global__ __launch_bounds__(512) void knode(
    const float* __restrict__ msg0, const float* __restrict__ msg1,
    const float* __restrict__ h, const float* __restrict__ Wl0,
    const float* __restrict__ Wl1, const float* __restrict__ WB0,
    const float* __restrict__ WB1, const float* __restrict__ Wc0,
    const float* __restrict__ Wc1, const unsigned short* __restrict__ wswz,
    float* __restrict__ out, float* __restrict__ stat) {
  extern __shared__ unsigned short klds[];
  // LDS tiles: 0 Wl0hi 1 Wl1hi 2 WB0hi 3 WB1hi; then 8 waves * 2048 act
  unsigned short* actS = klds + 4 * 4096;
  const int tid = threadIdx.x, w = tid >> 6, l = tid & 63;
  const int c = l & 15, q = l >> 4;
  for (int i = tid; i < 4096; i += 512) {
    int k = i >> 6, o = i & 63;
    int s = swz64(o, k);
    klds[s] = f2bf(Wl0[i]);
    klds[4096 + s] = f2bf(Wl1[i]);
    klds[2 * 4096 + s] = f2bf(WB0[i]);
    klds[3 * 4096 + s] = f2bf(WB1[i]);
  }
  __syncthreads();
  const int gw = blockIdx.x * 8 + w;
  const bool valid = (gw < NN / 16);
  const int gws = valid ? gw : 0;
  const int n0 = gws * 16;
  const int nc = n0 + c;
  unsigned short* actH = actS + w * 2048;
  unsigned short* actL = actH + 1024;
  const unsigned short* Wl0h = klds;
  const unsigned short* Wl1h = klds + 4096;
  const unsigned short* WB0h = klds + 2 * 4096;
  const unsigned short* WB1h = klds + 3 * 4096;
  const unsigned short* Wl0l = wswz;
  const unsigned short* Wl1l = wswz + 4096;
  const unsigned short* WB0l = wswz + 2 * 4096;
  const unsigned short* WB1l = wswz + 3 * 4096;
  const unsigned short* Wsc0t = wswz + 4 * 4096;
  const unsigned short* Wsc1t = wswz + 5 * 4096;

  // ---- stage 1+2: A = msg @ Wl, split x split (3-product) ----
  f32x4 aA0[4], aA1[3][4];
  {
    bf16x8 h0, l0, h1, l1;
    ldfrag2(msg0 + (size_t)nc * 64 + q * 8, h0, l0);
    ldfrag2(msg0 + (size_t)nc * 64 + 32 + q * 8, h1, l1);
#pragma unroll
    for (int nt = 0; nt < 4; ++nt) {
      int n = nt * 16 + c;
      f32x4 z = {0.f, 0.f, 0.f, 0.f};
      f32x4 v = mfma_(h0, wfrag(Wl0h, n, 0, q), z);
      v = mfma_(l0, wfrag(Wl0h, n, 0, q), v);
      v = mfma_(h0, wfrag(Wl0l, n, 0, q), v);
      v = mfma_(h1, wfrag(Wl0h, n, 1, q), v);
      v = mfma_(l1, wfrag(Wl0h, n, 1, q), v);
      v = mfma_(h1, wfrag(Wl0l, n, 1, q), v);
      aA0[nt] = v;
    }
#pragma unroll
    for (int x = 0; x < 3; ++x) {
      ldfrag2(msg1 + (size_t)nc * 192 + x * 64 + q * 8, h0, l0);
      ldfrag2(msg1 + (size_t)nc * 192 + x * 64 + 32 + q * 8, h1, l1);
#pragma unroll
      for (int nt = 0; nt < 4; ++nt) {
        int n = nt * 16 + c;
        f32x4 z = {0.f, 0.f, 0.f, 0.f};
        f32x4 v = mfma_(h0, wfrag(Wl1h, n, 0, q), z);
        v = mfma_(l0, wfrag(Wl1h, n, 0, q), v);
        v = mfma_(h0, wfrag(Wl1l, n, 0, q), v);
        v = mfma_(h1, wfrag(Wl1h, n, 1, q), v);
        v = mfma_(l1, wfrag(Wl1h, n, 1, q), v);
        v = mfma_(h1, wfrag(Wl1l, n, 1, q), v);
        aA1[x][nt] = v;
      }
    }
  }
  // ---- stage 3: polynomial (fp32, elementwise in D layout) ----
#pragma unroll
  for (int nt = 0; nt < 4; ++nt) {
    const int ch = nt * 16 + c;
    const float* wc0 = Wc0 + ch * 5;
    const float4 c1 = *reinterpret_cast<const float4*>(Wc1 + ch * 4);
#pragma unroll
    for (int r = 0; r < 4; ++r) {
      float A0v = aA0[nt][r];
      float ax = aA1[0][nt][r], ay = aA1[1][nt][r], az = aA1[2][nt][r];
      float vv = ax * ax + ay * ay + az * az;
      float A02 = A0v * A0v;
      float B0 = wc0[0] * A0v + wc0[1] * A02 + wc0[2] * vv +
                 wc0[3] * A02 * A0v + wc0[4] * A0v * vv;
      float sB = c1.x + c1.y * A0v + c1.z * A02 + c1.w * vv;
      aA0[nt][r] = B0;
      aA1[0][nt][r] = sB * ax;
      aA1[1][nt][r] = sB * ay;
      aA1[2][nt][r] = sB * az;
    }
  }
  // ---- stages 4-6 per component: split-transpose B, o = sc + B@WB ----
  float st0[4], sq0[4], st1[4];
#pragma unroll
  for (int nt = 0; nt < 4; ++nt) { st0[nt] = 0.f; sq0[nt] = 0.f; st1[nt] = 0.f; }
  const float* hrow = h + (size_t)nc * 256;

  // component 0 (scalar channel)
  {
#pragma unroll
    for (int nt = 0; nt < 4; ++nt)
#pragma unroll
      for (int r = 0; r < 4; ++r) {
        unsigned short hh, ll;
        splitbf(aA0[nt][r], hh, ll);
        int s = swz64(4 * q + r, nt * 16 + c);
        actH[s] = hh;
        actL[s] = ll;
      }
    __syncthreads();  // act write -> cross-lane frag read
    bf16x8 bh0 = *reinterpret_cast<const bf16x8*>(&actH[c * 64 + ((q ^ (c & 7)) << 3)]);
    bf16x8 bh1 = *reinterpret_cast<const bf16x8*>(&actH[c * 64 + (((4 + q) ^ (c & 7)) << 3)]);
    bf16x8 bl0 = *reinterpret_cast<const bf16x8*>(&actL[c * 64 + ((q ^ (c & 7)) << 3)]);
    bf16x8 bl1 = *reinterpret_cast<const bf16x8*>(&actL[c * 64 + (((4 + q) ^ (c & 7)) << 3)]);
    __syncthreads();  // frag read -> next component's act overwrite (WAR)
    bf16x8 ah0 = ldfrag(hrow + q * 8);
    bf16x8 ah1 = ldfrag(hrow + 32 + q * 8);
    f32x4 o[4];
#pragma unroll
    for (int nt = 0; nt < 4; ++nt) {
      int n = nt * 16 + c;
      f32x4 z = {0.f, 0.f, 0.f, 0.f};
      f32x4 v = mfma_(ah0, wfrag(Wsc0t, n, 0, q), z);
      v = mfma_(ah1, wfrag(Wsc0t, n, 1, q), v);
      v = mfma_(bh0, wfrag(WB0h, n, 0, q), v);
      v = mfma_(bh1, wfrag(WB0h, n, 1, q), v);
      v = mfma_(bl0, wfrag(WB0h, n, 0, q), v);
      v = mfma_(bl1, wfrag(WB0h, n, 1, q), v);
      v = mfma_(bh0, wfrag(WB0l, n, 0, q), v);
      v = mfma_(bh1, wfrag(WB0l, n, 1, q), v);
      o[nt] = v;
    }
    if (valid) {
#pragma unroll
      for (int nt = 0; nt < 4; ++nt) {
        const int ch = nt * 16 + c;
#pragma unroll
        for (int r = 0; r < 4; ++r) {
          float v = o[nt][r];
          out[(size_t)(n0 + 4 * q + r) * 256 + ch] = v;
          st0[nt] += v;
          sq0[nt] = fmaf(v, v, sq0[nt]);
        }
      }
    }
  }
  // components x = 0,1,2 (vector channels)
#pragma unroll
  for (int x = 0; x < 3; ++x) {
#pragma unroll
    for (int nt = 0; nt < 4; ++nt)
#pragma unroll
      for (int r = 0; r < 4; ++r) {
        unsigned short hh, ll;
        splitbf(aA1[x][nt][r], hh, ll);
        int s = swz64(4 * q + r, nt * 16 + c);
        actH[s] = hh;
        actL[s] = ll;
      }
    __syncthreads();  // act write -> cross-lane frag read
    bf16x8 bh0 = *reinterpret_cast<const bf16x8*>(&actH[c * 64 + ((q ^ (c & 7)) << 3)]);
    bf16x8 bh1 = *reinterpret_cast<const bf16x8*>(&actH[c * 64 + (((4 + q) ^ (c & 7)) << 3)]);
    bf16x8 bl0 = *reinterpret_cast<const bf16x8*>(&actL[c * 64 + ((q ^ (c & 7)) << 3)]);
    bf16x8 bl1 = *reinterpret_cast<const bf16x8*>(&actL[c * 64 + (((4 + q) ^ (c & 7)) << 3)]);
    __syncthreads();  // frag read -> next act overwrite (WAR)
    bf16x8 ah0, ah1;
#pragma unroll
    for (int i = 0; i < 8; ++i) {
      ah0[i] = (short)f2bf(hrow[64 + (q * 8 + i) * 3 + x]);
      ah1[i] = (short)f2bf(hrow[64 + (32 + q * 8 + i) * 3 + x]);
    }
    f32x4 o[4];
#pragma unroll
    for (int nt = 0; nt < 4; ++nt) {
      int n = nt * 16 + c;
      f32x4 z = {0.f, 0.f, 0.f, 0.f};
      f32x4 v = mfma_(ah0, wfrag(Wsc1t, n, 0, q), z);
      v = mfma_(ah1, wfrag(Wsc1t, n, 1, q), v);
      v = mfma_(bh0, wfrag(WB1h, n, 0, q), v);
      v = mfma_(bh1, wfrag(WB1h, n, 1, q), v);
      v = mfma_(bl0, wfrag(WB1h, n, 0, q), v);
      v = mfma_(bl1, wfrag(WB1h, n, 1, q), v);
      v = mfma_(bh0, wfrag(WB1l, n, 0, q), v);
      v = mfma_(bh1, wfrag(WB1l, n, 1, q), v);
      o[nt] = v;
    }
    if (valid) {
#pragma unroll
      for (int nt = 0; nt < 4; ++nt) {
        const int ch = nt * 16 + c;
#pragma unroll
        for (int r = 0; r < 4; ++r) {
          float v = o[nt][r];
          out[(size_t)(n0 + 4 * q + r) * 256 + 64 + 3 * ch + x] = v;
          st1[nt] = fmaf(v, v, st1[nt]);
        }
      }
    }
  }
  // ---- stats: reduce over q (same channel), one atomic set per wave ----
  if (valid) {
#pragma unroll
    for (int nt = 0; nt < 4; ++nt) {
      float v0 = st0[nt], v1 = sq0[nt], v2 = st1[nt];
      v0 += __shfl_xor(v0, 16); v0 += __shfl_xor(v0, 32);
      v1 += __shfl_xor(v1, 16); v1 += __shfl_xor(v1, 32);
      v2 += __shfl_xor(v2, 16); v2 += __shfl_xor(v2, 32);
      if (q == 0) {
        atomicAdd(stat + nt * 16 + c, v0);
        atomicAdd(stat + 64 + nt * 16 + c, v1);
        atomicAdd(stat + 128 + nt * 16 + c, v2);
      }
    }
  }
}

// ------------- Kernel E: normalize d_out in place (stats inlined) ----------
__global__ __launch_bounds__(256) void knorm(float* __restrict__ out,
                                             const float* __restrict__ stat,
                                             const float* __restrict__ gamma0,
                                             const float* __restrict__ gamma1,
                                             const float* __restrict__ beta0) {
  const int w = threadIdx.x >> 6, j = threadIdx.x & 63;
  const int n = blockIdx.x * 4 + w;
  const float invN = 1.0f / (float)NN;
  const float mu = stat[j] * invN;
  const float var = stat[64 + j] * invN - mu * mu;
  const float s0 = rsqrtf(var + 1e-5f) * gamma0[j];
  const float nr = stat[128 + j] * (invN / 3.0f);
  const float s1 = rsqrtf(nr + 1e-5f) * gamma1[j];
  const float b0 = beta0[j];
  float* orow = out + (size_t)n * 256;
  orow[j] = (orow[j] - mu) * s0 + b0;
#pragma unroll
  for (int x = 0; x < 3; ++x) orow[64 + 3 * j + x] *= s1;
}

extern "C" void kernel_launch(void* const* d_in, const int* in_sizes, int n_in,
                              void* d_out, int out_size, void* d_ws,
                              size_t ws_size, hipStream_t stream) {
  (void)in_sizes; (void)n_in; (void)out_size; (void)ws_size;
  const float* h = (const float*)d_in[0];
  const int* eidx = (const int*)d_in[1];
  const float* esh = (const float*)d_in[2];
  const float* erbf = (const float*)d_in[3];
  const float* Wup0 = (const float*)d_in[4];
  const float* Wup1 = (const float*)d_in[5];
  const float* M1 = (const float*)d_in[6];
  const float* M2 = (const float*)d_in[7];
  const float* M3 = (const float*)d_in[8];
  const float* M4 = (const float*)d_in[9];
  const float* Wl0 = (const float*)d_in[10];
  const float* Wl1 = (const float*)d_in[11];
  const float* Wsc0 = (const float*)d_in[12];
  const float* Wsc1 = (const float*)d_in[13];
  const float* Wc0 = (const float*)d_in[14];
  const float* Wc1 = (const float*)d_in[15];
  const float* WB0 = (const float*)d_in[16];
  const float* WB1 = (const float*)d_in[17];
  const float* gamma0 = (const float*)d_in[18];
  const float* beta0 = (const float*)d_in[19];
  const float* gamma1 = (const float*)d_in[20];

  float* ws = (float*)d_ws;
  unsigned short* upb = (unsigned short*)ws;  // N*64*4 fp16 (= N*128 f32)
  float* msg0 = ws + (size_t)NN * 256;        // N*64
  float* msg1 = ws + (size_t)NN * 320;        // N*192 (layout (n, x, c))
  float* stat = ws + (size_t)NN * 512;        // 384 floats
  unsigned short* wswz =
      (unsigned short*)(ws + (size_t)NN * 512 + 384);  // 6*4096 bf16
  float* outf = (float*)d_out;

  // sort scratch lives in d_out (overwritten by knode/knorm afterwards)
  int* hist = (int*)d_out;        // NN
  int* cursor = hist + NN;        // NN
  int* perm = cursor + NN;        // NE

  hipMemsetAsync(msg0, 0, ((size_t)NN * 256 + 384) * sizeof(float), stream);
  hipMemsetAsync(hist, 0, (size_t)NN * sizeof(int), stream);

  hipFuncSetAttribute((const void*)knode,
                      hipFuncAttributeMaxDynamicSharedMemorySize, 65536);

  ksort1_prep<<<EG_BLOCKS + 96, 256, 0, stream>>>(eidx, hist, Wl0, Wl1, WB0,
                                                  WB1, Wsc0, Wsc1, wswz);
  ksort2<<<1, 1024, 0, stream>>>(hist, cursor);
  ksort3_kup<<<EG_BLOCKS + NN / 4, 256, 0, stream>>>(eidx, cursor, perm, h,
                                                     Wup0, Wup1, upb);
  kedge<<<512, 512, 0, stream>>>(erbf, eidx, esh, M1, M2, M3, M4, upb, perm,
                                 msg0, msg1);
  knode<<<(NN / 16 + 7) / 8, 512, 65536, stream>>>(msg0, msg1, h, Wl0, Wl1,
                                                   WB0, WB1, Wc0, Wc1, wswz,
                                                   outf, stat);
  knorm<<<NN / 4, 256, 0, stream>>>(outf, stat, gamma0, gamma1, beta0);
}

// Round 18
// 483.305 us; speedup vs baseline: 1.0140x; 1.0140x over previous
//
#include <hip/hip_runtime.h>
#include <hip/hip_fp16.h>
#include <math.h>

#define NN 50000
#define NE 500000

typedef __attribute__((ext_vector_type(8))) short bf16x8;
typedef __attribute__((ext_vector_type(4))) float f32x4;

__device__ __forceinline__ float silu_f(float x) {
  return x / (1.0f + __expf(-x));
}
// fp32 -> bf16 (RNE)
__device__ __forceinline__ unsigned short f2bf(float x) {
  union { float f; unsigned u; } v;
  v.f = x;
  unsigned r = v.u + 0x7fffu + ((v.u >> 16) & 1u);
  return (unsigned short)(r >> 16);
}
// fp32 <-> fp16
__device__ __forceinline__ unsigned short f2h(float x) {
  __half h = __float2half(x);
  return *reinterpret_cast<unsigned short*>(&h);
}
__device__ __forceinline__ float h2f(unsigned short u) {
  __half h = *reinterpret_cast<__half*>(&u);
  return __half2float(h);
}
// split fp32 into bf16 hi + bf16 lo (x ~= hi + lo, ~2^-16 rel err)
__device__ __forceinline__ void splitbf(float x, unsigned short& hi_,
                                        unsigned short& lo_) {
  unsigned short h = f2bf(x);
  union { unsigned u; float f; } v;
  v.u = (unsigned)h << 16;
  hi_ = h;
  lo_ = f2bf(x - v.f);
}
// swizzled index into a [rows][64] bf16 tile: XOR 16B-unit with row&7
__device__ __forceinline__ int swz64(int row, int col) {
  return row * 64 + ((((col >> 3) ^ (row & 7)) << 3) | (col & 7));
}
// swizzled index into a [rows][32] bf16 tile: XOR 16B-unit with row&3
__device__ __forceinline__ int swz32(int row, int col) {
  return row * 32 + ((((col >> 3) ^ (row & 3)) << 3) | (col & 7));
}
// weight B-frag read from swizzled [64 out][64 in] bf16 tile
__device__ __forceinline__ bf16x8 wfrag(const unsigned short* Wt, int n,
                                        int kc, int q) {
  return *reinterpret_cast<const bf16x8*>(
      &Wt[n * 64 + (((kc * 4 + q) ^ (n & 7)) << 3)]);
}
// A-frag from 8 consecutive fp32 (single bf16)
__device__ __forceinline__ bf16x8 ldfrag(const float* p) {
  float4 f0 = *reinterpret_cast<const float4*>(p);
  float4 f1 = *reinterpret_cast<const float4*>(p + 4);
  bf16x8 a;
  a[0] = (short)f2bf(f0.x); a[1] = (short)f2bf(f0.y);
  a[2] = (short)f2bf(f0.z); a[3] = (short)f2bf(f0.w);
  a[4] = (short)f2bf(f1.x); a[5] = (short)f2bf(f1.y);
  a[6] = (short)f2bf(f1.z); a[7] = (short)f2bf(f1.w);
  return a;
}
// A-frag from 8 consecutive fp32, split hi/lo
__device__ __forceinline__ void ldfrag2(const float* p, bf16x8& hi,
                                        bf16x8& lo) {
  float4 f0 = *reinterpret_cast<const float4*>(p);
  float4 f1 = *reinterpret_cast<const float4*>(p + 4);
  float a[8] = {f0.x, f0.y, f0.z, f0.w, f1.x, f1.y, f1.z, f1.w};
#pragma unroll
  for (int i = 0; i < 8; ++i) {
    unsigned short h, l2;
    splitbf(a[i], h, l2);
    hi[i] = (short)h;
    lo[i] = (short)l2;
  }
}
__device__ __forceinline__ f32x4 mfma_(bf16x8 a, bf16x8 b, f32x4 cacc) {
  return __builtin_amdgcn_mfma_f32_16x16x32_bf16(a, b, cacc, 0, 0, 0);
}

// ---------- Sort kernels: counting sort of edges by receiver ----------
__global__ __launch_bounds__(256) void ksort1(const int* __restrict__ eidx,
                                              int* __restrict__ hist) {
  int e = blockIdx.x * 256 + threadIdx.x;
  if (e < NE) atomicAdd(&hist[eidx[NE + e]], 1);
}

__global__ __launch_bounds__(1024) void ksort2(const int* __restrict__ hist,
                                               int* __restrict__ cursor) {
  __shared__ int bs[1024];
  const int t = threadIdx.x;
  const int CH = (NN + 1023) / 1024;  // 49
  const int lo = t * CH, hi = (lo + CH < NN) ? lo + CH : NN;
  int s = 0;
  for (int i = lo; i < hi; ++i) s += hist[i];
  bs[t] = s;
  __syncthreads();
  for (int off = 1; off < 1024; off <<= 1) {
    int v = (t >= off) ? bs[t - off] : 0;
    __syncthreads();
    bs[t] += v;
    __syncthreads();
  }
  int run = bs[t] - s;  // exclusive prefix
  for (int i = lo; i < hi; ++i) {
    cursor[i] = run;
    run += hist[i];
  }
}

// ---------- Fused: ksort3 (scatter-permute) + kup (up-projections) ----------
// Blocks [0, EG) run the permute scatter; blocks [EG, EG+NN/4) run kup.
// The two halves are mutually independent; barriers are block-uniform.
#define EG_BLOCKS ((NE + 255) / 256)
__global__ __launch_bounds__(256) void ksort3_kup(
    const int* __restrict__ eidx, int* __restrict__ cursor,
    int* __restrict__ perm, const float* __restrict__ h,
    const float* __restrict__ Wup0, const float* __restrict__ Wup1,
    unsigned short* __restrict__ upb) {
  __shared__ float shd[4][256];
  if (blockIdx.x < EG_BLOCKS) {
    int e = blockIdx.x * 256 + threadIdx.x;
    if (e < NE) {
      int p = atomicAdd(&cursor[eidx[NE + e]], 1);
      perm[p] = e;
    }
    return;
  }
  const int w = threadIdx.x >> 6, j = threadIdx.x & 63;
  const int n = (blockIdx.x - EG_BLOCKS) * 4 + w;
  const float* hr = h + (size_t)n * 256;
#pragma unroll
  for (int t = 0; t < 4; ++t) shd[w][t * 64 + j] = hr[t * 64 + j];
  __syncthreads();  // cross-lane LDS handoff: always fence
  float a0 = 0.f, ax = 0.f, ay = 0.f, az = 0.f;
#pragma unroll 8
  for (int c = 0; c < 64; ++c) {
    float h0 = shd[w][c];
    float hx = shd[w][64 + 3 * c + 0];
    float hy = shd[w][64 + 3 * c + 1];
    float hz = shd[w][64 + 3 * c + 2];
    float w0 = Wup0[c * 64 + j];
    float w1 = Wup1[c * 64 + j];
    a0 = fmaf(h0, w0, a0);
    ax = fmaf(hx, w1, ax);
    ay = fmaf(hy, w1, ay);
    az = fmaf(hz, w1, az);
  }
  ushort4 pk;
  pk.x = f2h(a0);
  pk.y = f2h(ax);
  pk.z = f2h(ay);
  pk.w = f2h(az);
  *reinterpret_cast<ushort4*>(upb + ((size_t)n * 64 + j) * 4) = pk;
}

// ------------- Kernel B: MFMA edge MLP + messages + merged atomic scatter ----
// R13-exact (validated best: 220 us, absmax 0.75). 32 consecutive sorted
// edges per wave (two 16-edge MFMA tiles); slot remap (m>>2)*8+t*4+(m&3) so
// lane (c,q)'s merge chain covers 8 consecutive sorted edges.
__global__ __launch_bounds__(512) void kedge(
    const float* __restrict__ rbf, const int* __restrict__ eidx,
    const float* __restrict__ esh, const float* __restrict__ M1,
    const float* __restrict__ M2, const float* __restrict__ M3,
    const float* __restrict__ M4, const unsigned short* __restrict__ upb,
    const int* __restrict__ perm, float* __restrict__ msg0,
    float* __restrict__ msg1) {
  __shared__ unsigned short M1t[64 * 32];      // [out 64][in 32 (16 zero-pad)]
  __shared__ unsigned short M2t[64 * 64];      // [out][in]
  __shared__ unsigned short M3t[64 * 64];
  __shared__ unsigned short M4t[256 * 64];     // [out 256][in 64]
  __shared__ unsigned short actS[8][32 * 64];  // per-wave [slot 32][ch 64]
  const int tid = threadIdx.x;
  const int w = tid >> 6, l = tid & 63;
  const int c = l & 15, q = l >> 4;

  for (int i = tid; i < 2048; i += 512) {
    int o = i >> 5, k = i & 31;
    M1t[swz32(o, k)] = (k < 16) ? f2bf(M1[k * 64 + o]) : (unsigned short)0;
  }
  for (int i = tid; i < 4096; i += 512) {
    int k = i >> 6, o = i & 63;
    M2t[swz64(o, k)] = f2bf(M2[i]);
    M3t[swz64(o, k)] = f2bf(M3[i]);
  }
  for (int i = tid; i < 16384; i += 512) {
    int k = i >> 8, o = i & 255;
    M4t[swz64(o, k)] = f2bf(M4[i]);
  }
  __syncthreads();

  unsigned short* act = actS[w];
  const float inv3 = 0.57735026918962576f;
  const int NW = NE / 32;  // 15625 wave-groups of 32 sorted edges
  const int scq = (c >> 2) * 8 + (c & 3);  // slot of A-row c, tile 0

  for (int grp = blockIdx.x; grp < (NW + 7) / 8; grp += gridDim.x) {
    const int gw = grp * 8 + w;
    if (gw >= NW) continue;
    const int eb = gw * 32;

    // ---- MLP L1-L3 for both tiles; act rows = sorted slots ----
#pragma unroll
    for (int t = 0; t < 2; ++t) {
      const int sc = scq + t * 4;  // slot of A-row c in tile t
      bf16x8 a1 = {};
      if (q < 2) {
        const int pec = perm[eb + sc];
        const float* p = rbf + (size_t)pec * 16 + q * 8;
        float4 f0 = *reinterpret_cast<const float4*>(p);
        float4 f1 = *reinterpret_cast<const float4*>(p + 4);
        a1[0] = (short)f2bf(f0.x); a1[1] = (short)f2bf(f0.y);
        a1[2] = (short)f2bf(f0.z); a1[3] = (short)f2bf(f0.w);
        a1[4] = (short)f2bf(f1.x); a1[5] = (short)f2bf(f1.y);
        a1[6] = (short)f2bf(f1.z); a1[7] = (short)f2bf(f1.w);
      }
      f32x4 acc[4];
#pragma unroll
      for (int nt = 0; nt < 4; ++nt) {
        int n = nt * 16 + c;
        bf16x8 b = *reinterpret_cast<const bf16x8*>(&M1t[n * 32 + ((q ^ (n & 3)) << 3)]);
        f32x4 z = {0.f, 0.f, 0.f, 0.f};
        acc[nt] = __builtin_amdgcn_mfma_f32_16x16x32_bf16(a1, b, z, 0, 0, 0);
      }
#pragma unroll
      for (int nt = 0; nt < 4; ++nt)
#pragma unroll
        for (int r = 0; r < 4; ++r)
          act[swz64(q * 8 + t * 4 + r, nt * 16 + c)] = f2bf(silu_f(acc[nt][r]));

      // L2
      {
        bf16x8 a0 = *reinterpret_cast<const bf16x8*>(&act[sc * 64 + (((0 + q) ^ (sc & 7)) << 3)]);
        bf16x8 a1b = *reinterpret_cast<const bf16x8*>(&act[sc * 64 + (((4 + q) ^ (sc & 7)) << 3)]);
#pragma unroll
        for (int nt = 0; nt < 4; ++nt) {
          int n = nt * 16 + c;
          f32x4 z = {0.f, 0.f, 0.f, 0.f};
          acc[nt] = __builtin_amdgcn_mfma_f32_16x16x32_bf16(a0, wfrag(M2t, n, 0, q), z, 0, 0, 0);
          acc[nt] = __builtin_amdgcn_mfma_f32_16x16x32_bf16(a1b, wfrag(M2t, n, 1, q), acc[nt], 0, 0, 0);
        }
#pragma unroll
        for (int nt = 0; nt < 4; ++nt)
#pragma unroll
          for (int r = 0; r < 4; ++r)
            act[swz64(q * 8 + t * 4 + r, nt * 16 + c)] = f2bf(silu_f(acc[nt][r]));
      }
      // L3
      {
        bf16x8 a0 = *reinterpret_cast<const bf16x8*>(&act[sc * 64 + (((0 + q) ^ (sc & 7)) << 3)]);
        bf16x8 a1b = *reinterpret_cast<const bf16x8*>(&act[sc * 64 + (((4 + q) ^ (sc & 7)) << 3)]);
#pragma unroll
        for (int nt = 0; nt < 4; ++nt) {
          int n = nt * 16 + c;
          f32x4 z = {0.f, 0.f, 0.f, 0.f};
          acc[nt] = __builtin_amdgcn_mfma_f32_16x16x32_bf16(a0, wfrag(M3t, n, 0, q), z, 0, 0, 0);
          acc[nt] = __builtin_amdgcn_mfma_f32_16x16x32_bf16(a1b, wfrag(M3t, n, 1, q), acc[nt], 0, 0, 0);
        }
#pragma unroll
        for (int nt = 0; nt < 4; ++nt)
#pragma unroll
          for (int r = 0; r < 4; ++r)
            act[swz64(q * 8 + t * 4 + r, nt * 16 + c)] = f2bf(silu_f(acc[nt][r]));
      }
    }

    // ---- metadata for this lane's 8 consecutive sorted slots ----
    int sn[8], rvv[8];
    float4 shv[8];
#pragma unroll
    for (int r8 = 0; r8 < 8; ++r8) {
      const int e2 = perm[eb + 8 * q + r8];
      sn[r8] = eidx[e2];
      rvv[r8] = eidx[NE + e2];
      shv[r8] = *reinterpret_cast<const float4*>(esh + (size_t)e2 * 4);
    }
    // ---- hoist final-act A-frags per tile ----
    bf16x8 a0t[2], a1t[2];
#pragma unroll
    for (int t = 0; t < 2; ++t) {
      const int sc = scq + t * 4;
      a0t[t] = *reinterpret_cast<const bf16x8*>(&act[sc * 64 + (((0 + q) ^ (sc & 7)) << 3)]);
      a1t[t] = *reinterpret_cast<const bf16x8*>(&act[sc * 64 + (((4 + q) ^ (sc & 7)) << 3)]);
    }
    // ---- L4 fused with scatter; chain spans 8 consecutive sorted edges ----
#pragma unroll
    for (int j2 = 0; j2 < 4; ++j2) {
      const int ch = j2 * 16 + c;
      float acc0 = 0.f, accx = 0.f, accy = 0.f, accz = 0.f;
      int cur = rvv[0];
#pragma unroll
      for (int t = 0; t < 2; ++t) {
        ushort4 xv[4];
#pragma unroll
        for (int r = 0; r < 4; ++r)
          xv[r] = *reinterpret_cast<const ushort4*>(
              upb + ((size_t)sn[4 * t + r] * 64 + ch) * 4);
        f32x4 t4[4];
#pragma unroll
        for (int m = 0; m < 4; ++m) {
          int n = (m * 4 + j2) * 16 + c;
          f32x4 z = {0.f, 0.f, 0.f, 0.f};
          t4[m] = __builtin_amdgcn_mfma_f32_16x16x32_bf16(a0t[t], wfrag(M4t, n, 0, q), z, 0, 0, 0);
          t4[m] = __builtin_amdgcn_mfma_f32_16x16x32_bf16(a1t[t], wfrag(M4t, n, 1, q), t4[m], 0, 0, 0);
        }
#pragma unroll
        for (int r = 0; r < 4; ++r) {
          const int idx = 4 * t + r;
          float x0 = h2f(xv[r].x);
          float xx = h2f(xv[r].y);
          float xy = h2f(xv[r].z);
          float xz = h2f(xv[r].w);
          float t0v = t4[0][r], t1v = t4[1][r];
          float t2v = t4[2][r], t3v = t4[3][r];
          float4 sh4 = shv[idx];
          float dot = xx * sh4.y + xy * sh4.z + xz * sh4.w;
          float m0 = t0v * x0 * sh4.x + t3v * dot * inv3;
          float a1v = t1v * x0, b1v = t2v * sh4.x;
          float m1x = fmaf(a1v, sh4.y, b1v * xx);
          float m1y = fmaf(a1v, sh4.z, b1v * xy);
          float m1z = fmaf(a1v, sh4.w, b1v * xz);
          if (rvv[idx] != cur) {
            atomicAdd(msg0 + (size_t)cur * 64 + ch, acc0);
            atomicAdd(msg1 + (size_t)cur * 192 + ch, accx);
            atomicAdd(msg1 + (size_t)cur * 192 + 64 + ch, accy);
            atomicAdd(msg1 + (size_t)cur * 192 + 128 + ch, accz);
            cur = rvv[idx];
            acc0 = accx = accy = accz = 0.f;
          }
          acc0 += m0;
          accx += m1x;
          accy += m1y;
          accz += m1z;
        }
      }
      atomicAdd(msg0 + (size_t)cur * 64 + ch, acc0);
      atomicAdd(msg1 + (size_t)cur * 192 + ch, accx);
      atomicAdd(msg1 + (size_t)cur * 192 + 64 + ch, accy);
      atomicAdd(msg1 + (size_t)cur * 192 + 128 + ch, accz);
    }
  }
}

// ------------- Kernel C: MFMA node path, split-bf16, FULLY FENCED ----------
// (R10-exact, validated absmax 0.75)
__global__ __launch_bounds__(512) void knode(
    const float* __restrict__ msg0, const float* __restrict__ msg1,
    const float* __restrict__ h, const float* __restrict__ Wl0,
    const float* __restrict__ Wl1, const float* __restrict__ Wsc0,
    const float* __restrict__ Wsc1, const float* __restrict__ Wc0,
    const float* __restrict__ Wc1, const float* __restrict__ WB0,
    const float* __restrict__ WB1, float* __restrict__ out,
    float* __restrict__ stat) {
  extern __shared__ unsigned short klds[];
  unsigned short* actS = klds + 10 * 4096;  // 8 waves * 2048 (hi 1024, lo 1024)
  const int tid = threadIdx.x, w = tid >> 6, l = tid & 63;
  const int c = l & 15, q = l >> 4;
  for (int i = tid; i < 4096; i += 512) {
    int k = i >> 6, o = i & 63;
    int s = swz64(o, k);
    unsigned short hi, lo;
    splitbf(Wl0[i], hi, lo);
    klds[s] = hi; klds[4096 + s] = lo;
    splitbf(Wl1[i], hi, lo);
    klds[2 * 4096 + s] = hi; klds[3 * 4096 + s] = lo;
    klds[4 * 4096 + s] = f2bf(Wsc0[i]);
    klds[5 * 4096 + s] = f2bf(Wsc1[i]);
    splitbf(WB0[i], hi, lo);
    klds[6 * 4096 + s] = hi; klds[7 * 4096 + s] = lo;
    splitbf(WB1[i], hi, lo);
    klds[8 * 4096 + s] = hi; klds[9 * 4096 + s] = lo;
  }
  __syncthreads();
  const int gw = blockIdx.x * 8 + w;
  const bool valid = (gw < NN / 16);
  const int gws = valid ? gw : 0;
  const int n0 = gws * 16;
  const int nc = n0 + c;
  unsigned short* actH = actS + w * 2048;
  unsigned short* actL = actH + 1024;
  const unsigned short* Wl0h = klds;
  const unsigned short* Wl0l = klds + 4096;
  const unsigned short* Wl1h = klds + 2 * 4096;
  const unsigned short* Wl1l = klds + 3 * 4096;
  const unsigned short* Wsc0t = klds + 4 * 4096;
  const unsigned short* Wsc1t = klds + 5 * 4096;
  const unsigned short* WB0h = klds + 6 * 4096;
  const unsigned short* WB0l = klds + 7 * 4096;
  const unsigned short* WB1h = klds + 8 * 4096;
  const unsigned short* WB1l = klds + 9 * 4096;

  // ---- stage 1+2: A = msg @ Wl, split x split (3-product) ----
  f32x4 aA0[4], aA1[3][4];
  {
    bf16x8 h0, l0, h1, l1;
    ldfrag2(msg0 + (size_t)nc * 64 + q * 8, h0, l0);
    ldfrag2(msg0 + (size_t)nc * 64 + 32 + q * 8, h1, l1);
#pragma unroll
    for (int nt = 0; nt < 4; ++nt) {
      int n = nt * 16 + c;
      f32x4 z = {0.f, 0.f, 0.f, 0.f};
      f32x4 v = mfma_(h0, wfrag(Wl0h, n, 0, q), z);
      v = mfma_(l0, wfrag(Wl0h, n, 0, q), v);
      v = mfma_(h0, wfrag(Wl0l, n, 0, q), v);
      v = mfma_(h1, wfrag(Wl0h, n, 1, q), v);
      v = mfma_(l1, wfrag(Wl0h, n, 1, q), v);
      v = mfma_(h1, wfrag(Wl0l, n, 1, q), v);
      aA0[nt] = v;
    }
#pragma unroll
    for (int x = 0; x < 3; ++x) {
      ldfrag2(msg1 + (size_t)nc * 192 + x * 64 + q * 8, h0, l0);
      ldfrag2(msg1 + (size_t)nc * 192 + x * 64 + 32 + q * 8, h1, l1);
#pragma unroll
      for (int nt = 0; nt < 4; ++nt) {
        int n = nt * 16 + c;
        f32x4 z = {0.f, 0.f, 0.f, 0.f};
        f32x4 v = mfma_(h0, wfrag(Wl1h, n, 0, q), z);
        v = mfma_(l0, wfrag(Wl1h, n, 0, q), v);
        v = mfma_(h0, wfrag(Wl1l, n, 0, q), v);
        v = mfma_(h1, wfrag(Wl1h, n, 1, q), v);
        v = mfma_(l1, wfrag(Wl1h, n, 1, q), v);
        v = mfma_(h1, wfrag(Wl1l, n, 1, q), v);
        aA1[x][nt] = v;
      }
    }
  }
  // ---- stage 3: polynomial (fp32, elementwise in D layout) ----
#pragma unroll
  for (int nt = 0; nt < 4; ++nt) {
    const int ch = nt * 16 + c;
    const float* wc0 = Wc0 + ch * 5;
    const float4 c1 = *reinterpret_cast<const float4*>(Wc1 + ch * 4);
#pragma unroll
    for (int r = 0; r < 4; ++r) {
      float A0v = aA0[nt][r];
      float ax = aA1[0][nt][r], ay = aA1[1][nt][r], az = aA1[2][nt][r];
      float vv = ax * ax + ay * ay + az * az;
      float A02 = A0v * A0v;
      float B0 = wc0[0] * A0v + wc0[1] * A02 + wc0[2] * vv +
                 wc0[3] * A02 * A0v + wc0[4] * A0v * vv;
      float sB = c1.x + c1.y * A0v + c1.z * A02 + c1.w * vv;
      aA0[nt][r] = B0;
      aA1[0][nt][r] = sB * ax;
      aA1[1][nt][r] = sB * ay;
      aA1[2][nt][r] = sB * az;
    }
  }
  // ---- stages 4-6 per component: split-transpose B, o = sc + B@WB ----
  float st0[4], sq0[4], st1[4];
#pragma unroll
  for (int nt = 0; nt < 4; ++nt) { st0[nt] = 0.f; sq0[nt] = 0.f; st1[nt] = 0.f; }
  const float* hrow = h + (size_t)nc * 256;

  // component 0 (scalar channel)
  {
#pragma unroll
    for (int nt = 0; nt < 4; ++nt)
#pragma unroll
      for (int r = 0; r < 4; ++r) {
        unsigned short hh, ll;
        splitbf(aA0[nt][r], hh, ll);
        int s = swz64(4 * q + r, nt * 16 + c);
        actH[s] = hh;
        actL[s] = ll;
      }
    __syncthreads();  // act write -> cross-lane frag read
    bf16x8 bh0 = *reinterpret_cast<const bf16x8*>(&actH[c * 64 + ((q ^ (c & 7)) << 3)]);
    bf16x8 bh1 = *reinterpret_cast<const bf16x8*>(&actH[c * 64 + (((4 + q) ^ (c & 7)) << 3)]);
    bf16x8 bl0 = *reinterpret_cast<const bf16x8*>(&actL[c * 64 + ((q ^ (c & 7)) << 3)]);
    bf16x8 bl1 = *reinterpret_cast<const bf16x8*>(&actL[c * 64 + (((4 + q) ^ (c & 7)) << 3)]);
    __syncthreads();  // frag read -> next component's act overwrite (WAR)
    bf16x8 ah0 = ldfrag(hrow + q * 8);
    bf16x8 ah1 = ldfrag(hrow + 32 + q * 8);
    f32x4 o[4];
#pragma unroll
    for (int nt = 0; nt < 4; ++nt) {
      int n = nt * 16 + c;
      f32x4 z = {0.f, 0.f, 0.f, 0.f};
      f32x4 v = mfma_(ah0, wfrag(Wsc0t, n, 0, q), z);
      v = mfma_(ah1, wfrag(Wsc0t, n, 1, q), v);
      v = mfma_(bh0, wfrag(WB0h, n, 0, q), v);
      v = mfma_(bh1, wfrag(WB0h, n, 1, q), v);
      v = mfma_(bl0, wfrag(WB0h, n, 0, q), v);
      v = mfma_(bl1, wfrag(WB0h, n, 1, q), v);
      v = mfma_(bh0, wfrag(WB0l, n, 0, q), v);
      v = mfma_(bh1, wfrag(WB0l, n, 1, q), v);
      o[nt] = v;
    }
    if (valid) {
#pragma unroll
      for (int nt = 0; nt < 4; ++nt) {
        const int ch = nt * 16 + c;
#pragma unroll
        for (int r = 0; r < 4; ++r) {
          float v = o[nt][r];
          out[(size_t)(n0 + 4 * q + r) * 256 + ch] = v;
          st0[nt] += v;
          sq0[nt] = fmaf(v, v, sq0[nt]);
        }
      }
    }
  }
  // components x = 0,1,2 (vector channels)
#pragma unroll
  for (int x = 0; x < 3; ++x) {
#pragma unroll
    for (int nt = 0; nt < 4; ++nt)
#pragma unroll
      for (int r = 0; r < 4; ++r) {
        unsigned short hh, ll;
        splitbf(aA1[x][nt][r], hh, ll);
        int s = swz64(4 * q + r, nt * 16 + c);
        actH[s] = hh;
        actL[s] = ll;
      }
    __syncthreads();  // act write -> cross-lane frag read
    bf16x8 bh0 = *reinterpret_cast<const bf16x8*>(&actH[c * 64 + ((q ^ (c & 7)) << 3)]);
    bf16x8 bh1 = *reinterpret_cast<const bf16x8*>(&actH[c * 64 + (((4 + q) ^ (c & 7)) << 3)]);
    bf16x8 bl0 = *reinterpret_cast<const bf16x8*>(&actL[c * 64 + ((q ^ (c & 7)) << 3)]);
    bf16x8 bl1 = *reinterpret_cast<const bf16x8*>(&actL[c * 64 + (((4 + q) ^ (c & 7)) << 3)]);
    __syncthreads();  // frag read -> next act overwrite (WAR)
    bf16x8 ah0, ah1;
#pragma unroll
    for (int i = 0; i < 8; ++i) {
      ah0[i] = (short)f2bf(hrow[64 + (q * 8 + i) * 3 + x]);
      ah1[i] = (short)f2bf(hrow[64 + (32 + q * 8 + i) * 3 + x]);
    }
    f32x4 o[4];
#pragma unroll
    for (int nt = 0; nt < 4; ++nt) {
      int n = nt * 16 + c;
      f32x4 z = {0.f, 0.f, 0.f, 0.f};
      f32x4 v = mfma_(ah0, wfrag(Wsc1t, n, 0, q), z);
      v = mfma_(ah1, wfrag(Wsc1t, n, 1, q), v);
      v = mfma_(bh0, wfrag(WB1h, n, 0, q), v);
      v = mfma_(bh1, wfrag(WB1h, n, 1, q), v);
      v = mfma_(bl0, wfrag(WB1h, n, 0, q), v);
      v = mfma_(bl1, wfrag(WB1h, n, 1, q), v);
      v = mfma_(bh0, wfrag(WB1l, n, 0, q), v);
      v = mfma_(bh1, wfrag(WB1l, n, 1, q), v);
      o[nt] = v;
    }
    if (valid) {
#pragma unroll
      for (int nt = 0; nt < 4; ++nt) {
        const int ch = nt * 16 + c;
#pragma unroll
        for (int r = 0; r < 4; ++r) {
          float v = o[nt][r];
          out[(size_t)(n0 + 4 * q + r) * 256 + 64 + 3 * ch + x] = v;
          st1[nt] = fmaf(v, v, st1[nt]);
        }
      }
    }
  }
  // ---- stats: reduce over q (same channel), one atomic set per wave ----
  if (valid) {
#pragma unroll
    for (int nt = 0; nt < 4; ++nt) {
      float v0 = st0[nt], v1 = sq0[nt], v2 = st1[nt];
      v0 += __shfl_xor(v0, 16); v0 += __shfl_xor(v0, 32);
      v1 += __shfl_xor(v1, 16); v1 += __shfl_xor(v1, 32);
      v2 += __shfl_xor(v2, 16); v2 += __shfl_xor(v2, 32);
      if (q == 0) {
        atomicAdd(stat + nt * 16 + c, v0);
        atomicAdd(stat + 64 + nt * 16 + c, v1);
        atomicAdd(stat + 128 + nt * 16 + c, v2);
      }
    }
  }
}

// ------------- Kernel D: finalize statistics (1 block, 64 threads) ----------
__global__ void kstat(const float* __restrict__ stat_in,
                      float* __restrict__ stat_out,
                      const float* __restrict__ gamma0,
                      const float* __restrict__ gamma1) {
  const int j = threadIdx.x;
  const float invN = 1.0f / (float)NN;
  float mu = stat_in[j] * invN;
  float var = stat_in[64 + j] * invN - mu * mu;
  float s0 = rsqrtf(var + 1e-5f) * gamma0[j];
  float nr = stat_in[128 + j] * (invN / 3.0f);
  float s1 = rsqrtf(nr + 1e-5f) * gamma1[j];
  stat_out[j] = mu;
  stat_out[64 + j] = s0;
  stat_out[128 + j] = s1;
}

// ------------- Kernel E: normalize d_out in place ----------
__global__ __launch_bounds__(256) void knorm(float* __restrict__ out,
                                             const float* __restrict__ stat,
                                             const float* __restrict__ beta0) {
  const int w = threadIdx.x >> 6, j = threadIdx.x & 63;
  const int n = blockIdx.x * 4 + w;
  const float mu = stat[192 + j], s0 = stat[256 + j], s1 = stat[320 + j];
  const float b0 = beta0[j];
  float* orow = out + (size_t)n * 256;
  orow[j] = (orow[j] - mu) * s0 + b0;
#pragma unroll
  for (int x = 0; x < 3; ++x) orow[64 + 3 * j + x] *= s1;
}

extern "C" void kernel_launch(void* const* d_in, const int* in_sizes, int n_in,
                              void* d_out, int out_size, void* d_ws,
                              size_t ws_size, hipStream_t stream) {
  (void)in_sizes; (void)n_in; (void)out_size; (void)ws_size;
  const float* h = (const float*)d_in[0];
  const int* eidx = (const int*)d_in[1];
  const float* esh = (const float*)d_in[2];
  const float* erbf = (const float*)d_in[3];
  const float* Wup0 = (const float*)d_in[4];
  const float* Wup1 = (const float*)d_in[5];
  const float* M1 = (const float*)d_in[6];
  const float* M2 = (const float*)d_in[7];
  const float* M3 = (const float*)d_in[8];
  const float* M4 = (const float*)d_in[9];
  const float* Wl0 = (const float*)d_in[10];
  const float* Wl1 = (const float*)d_in[11];
  const float* Wsc0 = (const float*)d_in[12];
  const float* Wsc1 = (const float*)d_in[13];
  const float* Wc0 = (const float*)d_in[14];
  const float* Wc1 = (const float*)d_in[15];
  const float* WB0 = (const float*)d_in[16];
  const float* WB1 = (const float*)d_in[17];
  const float* gamma0 = (const float*)d_in[18];
  const float* beta0 = (const float*)d_in[19];
  const float* gamma1 = (const float*)d_in[20];

  float* ws = (float*)d_ws;
  unsigned short* upb = (unsigned short*)ws;  // N*64*4 fp16 (= N*128 f32)
  float* msg0 = ws + (size_t)NN * 256;        // N*64
  float* msg1 = ws + (size_t)NN * 320;        // N*192 (layout (n, x, c))
  float* stat = ws + (size_t)NN * 512;        // 384 floats
  float* outf = (float*)d_out;

  // sort scratch lives in d_out (overwritten by knode/knorm afterwards)
  int* hist = (int*)d_out;        // NN
  int* cursor = hist + NN;        // NN
  int* perm = cursor + NN;        // NE

  hipMemsetAsync(msg0, 0, ((size_t)NN * 256 + 384) * sizeof(float), stream);
  hipMemsetAsync(hist, 0, (size_t)NN * sizeof(int), stream);

  hipFuncSetAttribute((const void*)knode,
                      hipFuncAttributeMaxDynamicSharedMemorySize, 114688);

  ksort1<<<EG_BLOCKS, 256, 0, stream>>>(eidx, hist);
  ksort2<<<1, 1024, 0, stream>>>(hist, cursor);
  ksort3_kup<<<EG_BLOCKS + NN / 4, 256, 0, stream>>>(eidx, cursor, perm, h,
                                                     Wup0, Wup1, upb);
  kedge<<<512, 512, 0, stream>>>(erbf, eidx, esh, M1, M2, M3, M4, upb, perm,
                                 msg0, msg1);
  knode<<<(NN / 16 + 7) / 8, 512, 114688, stream>>>(
      msg0, msg1, h, Wl0, Wl1, Wsc0, Wsc1, Wc0, Wc1, WB0, WB1, outf, stat);
  kstat<<<1, 64, 0, stream>>>(stat, stat + 192, gamma0, gamma1);
  knorm<<<NN / 4, 256, 0, stream>>>(outf, stat, beta0);
}